// Round 5
// baseline (58.595 us; speedup 1.0000x reference)
//
#include <hip/hip_runtime.h>

#define C_DIM 512
#define HID   256
#define B_DIM 8
#define L_DIM 196
#define LT    14               // l-tile per block (phase 1)
#define NCH   4                // c-chunks = waves per block (phase 1)
#define CCH   (C_DIM/NCH)      // 128 c per chunk
#define HS    64               // h-strip = lane width (phase 1)
#define ROWS  7                // i-rows per wave (phase 2)
#define NIG   (L_DIM/ROWS)     // 28 i-groups
#define JCL   14               // j per chunk (phase 2)
#define NJC   (L_DIM/JCL)      // 14 j-chunks
#define P_ELEMS (B_DIM*L_DIM*HID)

// Phase 1: p1[b,l,h] = sum_c f1[b,c,l]*W1[c,h] + b1[h]
//          p2[b,l,h] = sum_c f2[b,c,l]*W1[C+c,h]
// grid = (8*14*4, 2), block = 256 = 4 waves (wave = c-chunk, lane = h in strip).
// f rows are wave-uniform -> forced onto the scalar (s_load) path; no big LDS.
__global__ __launch_bounds__(256) void compute_p_kernel(
    const float* __restrict__ f1, const float* __restrict__ f2,
    const float* __restrict__ W1, const float* __restrict__ b1,
    const float* __restrict__ b2,
    float* __restrict__ p1, float* __restrict__ p2,
    float* __restrict__ out) {
  // re-init output accumulators every call (pair_kernel atomicAdds into them;
  // kernel ordering on the stream makes this visible before pair_kernel runs)
  if (blockIdx.x == 0 && blockIdx.y == 0 && threadIdx.x < B_DIM)
    out[threadIdx.x] = (float)(L_DIM * L_DIM) * b2[0];

  const int which = blockIdx.y;
  const int hs = blockIdx.x & 3;
  const int bt = blockIdx.x >> 2;               // 0..111
  const int b  = bt / 14;
  const int l0 = (bt % 14) * LT;
  const int lane  = threadIdx.x & 63;
  // wave id == c-chunk; readfirstlane makes it SGPR-resident so the f-row
  // addresses are provably wave-uniform -> compiler emits s_load (SMEM pipe).
  const int chunk   = threadIdx.x >> 6;         // 0..3 (control flow)
  const int chunk_u = __builtin_amdgcn_readfirstlane(chunk);
  const int h = hs * HS + lane;

  const float* __restrict__ f = which ? f2 : f1;
  const float* __restrict__ W = W1 + which * C_DIM * HID;
  float* __restrict__ p = which ? p2 : p1;

  __shared__ float comb[2][HS][LT + 1];         // 7.7 KB (15-stride: conflict-free)

  float acc[LT];
  #pragma unroll
  for (int lt = 0; lt < LT; ++lt) acc[lt] = 0.0f;

  const float* __restrict__ frow0 = f + (b * C_DIM + chunk_u * CCH) * L_DIM + l0;
  const float* __restrict__ Wc    = W + (chunk_u * CCH) * HID + h;

  #pragma unroll 4
  for (int c = 0; c < CCH; ++c) {
    const float w = Wc[c * HID];                // per-lane, 256B coalesced, L2-hit
    const float* __restrict__ fr = frow0 + c * L_DIM;  // wave-uniform -> s_load
    #pragma unroll
    for (int lt = 0; lt < LT; ++lt)
      acc[lt] = fmaf(fr[lt], w, acc[lt]);       // SGPR src0, VGPR src1 (legal mix)
  }

  // cross-wave tree-combine of the 4 c-chunks
  if (chunk >= 2) {
    #pragma unroll
    for (int lt = 0; lt < LT; ++lt) comb[chunk - 2][lane][lt] = acc[lt];
  }
  __syncthreads();
  if (chunk < 2) {
    #pragma unroll
    for (int lt = 0; lt < LT; ++lt) acc[lt] += comb[chunk][lane][lt];
  }
  __syncthreads();
  if (chunk == 1) {
    #pragma unroll
    for (int lt = 0; lt < LT; ++lt) comb[0][lane][lt] = acc[lt];
  }
  __syncthreads();
  if (chunk == 0) {
    const float bias = which ? 0.0f : b1[h];    // fold b1 into p1 only
    #pragma unroll
    for (int lt = 0; lt < LT; ++lt)
      p[(b * L_DIM + l0 + lt) * HID + h] = acc[lt] + comb[0][lane][lt] + bias;
  }
}

// Phase 2 (+final sum): wave = 7 i-rows x one 14-j chunk; lane = 4 h-channels.
// Each block (2 waves, same b/jc) reduces to ONE scalar and atomicAdds out[b].
// grid = 8*14*14 = 1568 blocks of 128 threads -> 3136 waves (~3/SIMD).
__global__ __launch_bounds__(128) void pair_kernel(
    const float* __restrict__ p1, const float* __restrict__ p2,
    const float* __restrict__ W2, float* __restrict__ out) {
  const int lane = threadIdx.x & 63;
  const int wave = threadIdx.x >> 6;            // 0..1
  const int b   = blockIdx.x / (NJC * (NIG / 2));   // /196
  const int r   = blockIdx.x % (NJC * (NIG / 2));
  const int jc  = r / (NIG / 2);                // 0..13 (same for both waves)
  const int wi  = (r % (NIG / 2)) * 2 + wave;   // 0..27

  const float4 w = *(const float4*)(W2 + lane * 4);
  const float* __restrict__ p1b = p1 + (b * L_DIM) * HID + lane * 4;

  float4 a[ROWS];
  #pragma unroll
  for (int k = 0; k < ROWS; ++k)
    a[k] = *(const float4*)(p1b + (wi + k * NIG) * HID);  // i = wi + k*28

  float s[ROWS];
  #pragma unroll
  for (int k = 0; k < ROWS; ++k) s[k] = 0.0f;

  const float4* __restrict__ vp =
      (const float4*)(p2 + (b * L_DIM + jc * JCL) * HID) + lane;

#define PAIR_BODY(vv)                                          \
  {                                                            \
    _Pragma("unroll")                                          \
    for (int k = 0; k < ROWS; ++k) {                           \
      s[k] = fmaf(fmaxf(a[k].x + (vv).x, 0.f), w.x, s[k]);     \
      s[k] = fmaf(fmaxf(a[k].y + (vv).y, 0.f), w.y, s[k]);     \
      s[k] = fmaf(fmaxf(a[k].z + (vv).z, 0.f), w.z, s[k]);     \
      s[k] = fmaf(fmaxf(a[k].w + (vv).w, 0.f), w.w, s[k]);     \
    }                                                          \
  }

  float4 v = vp[0];
  #pragma unroll
  for (int j = 0; j < JCL - 1; ++j) {           // branch-free preload pipeline
    float4 vn = vp[(j + 1) * (HID / 4)];
    PAIR_BODY(v);
    v = vn;
  }
  PAIR_BODY(v);
#undef PAIR_BODY

  // collapse rows, then lanes (sums over h since each lane held 4 channels)
  float t = 0.0f;
  #pragma unroll
  for (int k = 0; k < ROWS; ++k) t += s[k];
  #pragma unroll
  for (int off = 32; off > 0; off >>= 1) t += __shfl_down(t, off);

  __shared__ float sred[2];
  if (lane == 0) sred[wave] = t;
  __syncthreads();
  if (threadIdx.x == 0)
    atomicAdd(&out[b], sred[0] + sred[1]);      // 1568 atomics over 8 addresses
}

extern "C" void kernel_launch(void* const* d_in, const int* in_sizes, int n_in,
                              void* d_out, int out_size, void* d_ws, size_t ws_size,
                              hipStream_t stream) {
  const float* f1 = (const float*)d_in[0];   // [B, C, 14, 14]
  const float* f2 = (const float*)d_in[1];
  const float* W1 = (const float*)d_in[2];   // [2C, HID]
  const float* b1 = (const float*)d_in[3];   // [HID]
  const float* W2 = (const float*)d_in[4];   // [HID, 1]
  const float* b2 = (const float*)d_in[5];   // [1]
  float* out = (float*)d_out;                // [B, 1]

  float* p1 = (float*)d_ws;
  float* p2 = p1 + P_ELEMS;

  dim3 g1(B_DIM * 14 * 4, 2);                // (b, l-tile, h-strip) x side
  compute_p_kernel<<<g1, 256, 0, stream>>>(f1, f2, W1, b1, b2, p1, p2, out);

  pair_kernel<<<B_DIM * NJC * (NIG / 2), 128, 0, stream>>>(p1, p2, W2, out);
}

// Round 6
// 40.268 us; speedup vs baseline: 1.4551x; 1.4551x over previous
//
#include <hip/hip_runtime.h>

#define C_DIM 512
#define HID   256
#define B_DIM 8
#define L_DIM 196
#define NCH   4                 // c-chunks = waves per block (phase 1)
#define CCH   (C_DIM/NCH)       // 128 c per chunk
#define LG    7                 // l-rows per block (phase 1)
#define NLG   (L_DIM/LG)        // 28 l-groups
#define ROWS  14                // i-rows per wave (phase 2)
#define LT    14
#define NJC   14                // j-chunks (phase 2)
#define JCL   (L_DIM/NJC)       // 14 j per chunk
#define PAIR_BLOCKS ((B_DIM*NJC*LT)/4)      // 392
#define P_ELEMS        (B_DIM*L_DIM*HID)
#define PARTIAL_ELEMS  (B_DIM*NJC*L_DIM)

// Phase 1: p1[b,l,h] = sum_c f1[b,c,l]*W1[c,h] + b1[h]
//          p2[b,l,h] = sum_c f2[b,c,l]*W1[C+c,h]
// grid = (8*28, 2), block = 256 = 4 waves (wave = c-chunk of 128).
// Lane owns 4 h (float4 W loads -> 56 VALU cyc per 16B HBM load) x 7 l = 28 accs.
__global__ __launch_bounds__(256) void compute_p_kernel(
    const float* __restrict__ f1, const float* __restrict__ f2,
    const float* __restrict__ W1, const float* __restrict__ b1,
    float* __restrict__ p1, float* __restrict__ p2) {
  const int which = blockIdx.y;
  const int b  = blockIdx.x / NLG;
  const int lg = blockIdx.x % NLG;
  const int l0 = lg * LG;
  const int lane  = threadIdx.x & 63;
  const int chunk = threadIdx.x >> 6;           // 0..3 (wave = c-chunk)

  const float* __restrict__ f = which ? f2 : f1;
  const float* __restrict__ W = W1 + which * C_DIM * HID;
  float* __restrict__ p = which ? p2 : p1;

  __shared__ float flds[C_DIM][8];              // 16 KB, 7 l padded to 8
  __shared__ float comb[2][64][32];             // 16 KB, XOR-swizzled b128 access

  // stage f slice [512 c][7 l] (3584 floats, 14 scalar loads/thread, pipelined)
  for (int idx = threadIdx.x; idx < C_DIM * LG; idx += 256) {
    const int c  = idx / LG;
    const int lt = idx - c * LG;
    flds[c][lt] = f[(b * C_DIM + c) * L_DIM + l0 + lt];
  }

  float4 acc[LG];
  #pragma unroll
  for (int l = 0; l < LG; ++l) acc[l] = make_float4(0.f, 0.f, 0.f, 0.f);
  __syncthreads();

  const float4* __restrict__ Wv = (const float4*)W + chunk * CCH * (HID / 4) + lane;
  #pragma unroll 4
  for (int c = 0; c < CCH; ++c) {
    const int cc = chunk * CCH + c;
    const float4 wv = Wv[c * (HID / 4)];        // 1KB/wave from HBM/L2
    const float4 fa = *(const float4*)&flds[cc][0];   // broadcast b128
    const float4 fb = *(const float4*)&flds[cc][4];   // broadcast b128 (lane 7 pad)
    const float fl[LG] = {fa.x, fa.y, fa.z, fa.w, fb.x, fb.y, fb.z};
    #pragma unroll
    for (int l = 0; l < LG; ++l) {
      acc[l].x = fmaf(fl[l], wv.x, acc[l].x);
      acc[l].y = fmaf(fl[l], wv.y, acc[l].y);
      acc[l].z = fmaf(fl[l], wv.z, acc[l].z);
      acc[l].w = fmaf(fl[l], wv.w, acc[l].w);
    }
  }

  // tree-combine 4 c-chunk waves; XOR swizzle keeps b128 LDS conflict-free
  const int swz = (lane & 7) << 2;              // 0,4,..,28 floats
  if (chunk >= 2) {
    #pragma unroll
    for (int l = 0; l < LG; ++l)
      *(float4*)&comb[chunk - 2][lane][(l * 4) ^ swz] = acc[l];
  }
  __syncthreads();
  if (chunk < 2) {
    #pragma unroll
    for (int l = 0; l < LG; ++l) {
      const float4 o = *(const float4*)&comb[chunk][lane][(l * 4) ^ swz];
      acc[l].x += o.x; acc[l].y += o.y; acc[l].z += o.z; acc[l].w += o.w;
    }
  }
  __syncthreads();
  if (chunk == 1) {
    #pragma unroll
    for (int l = 0; l < LG; ++l)
      *(float4*)&comb[0][lane][(l * 4) ^ swz] = acc[l];
  }
  __syncthreads();
  if (chunk == 0) {
    float4 bias = make_float4(0.f, 0.f, 0.f, 0.f);
    if (!which) bias = *(const float4*)(b1 + lane * 4);   // fold b1 into p1
    #pragma unroll
    for (int l = 0; l < LG; ++l) {
      const float4 o = *(const float4*)&comb[0][lane][(l * 4) ^ swz];
      float4 r;
      r.x = acc[l].x + o.x + bias.x;
      r.y = acc[l].y + o.y + bias.y;
      r.z = acc[l].z + o.z + bias.z;
      r.w = acc[l].w + o.w + bias.w;
      *(float4*)(p + (b * L_DIM + l0 + l) * HID + lane * 4) = r;  // 1KB/row coalesced
    }
  }
}

// Phase 2 (round-4 exact): wave = 14 i-rows x one 14-j chunk.
// partial[b,jc,i] = sum_{j in chunk jc} relu(p1[b,i,:]+p2[b,j,:]).W2
__global__ __launch_bounds__(256) void pair_kernel(
    const float* __restrict__ p1, const float* __restrict__ p2,
    const float* __restrict__ W2, float* __restrict__ partial) {
  const int lane = threadIdx.x & 63;
  const int wid  = blockIdx.x * 4 + (threadIdx.x >> 6);   // 0..1567
  const int b  = wid / (NJC * LT);
  const int r  = wid % (NJC * LT);
  const int jc = r / LT;                                  // 0..13
  const int wi = r % LT;                                  // 0..13

  const float4 w = *(const float4*)(W2 + lane * 4);
  const float* __restrict__ p1b = p1 + (b * L_DIM) * HID + lane * 4;

  float4 a[ROWS];
  #pragma unroll
  for (int k = 0; k < ROWS; ++k)
    a[k] = *(const float4*)(p1b + (wi + k * LT) * HID);   // i = wi + k*14

  float s[ROWS];
  #pragma unroll
  for (int k = 0; k < ROWS; ++k) s[k] = 0.0f;

  const float4* __restrict__ vp =
      (const float4*)(p2 + (b * L_DIM + jc * JCL) * HID) + lane;

#define PAIR_BODY(vv)                                          \
  {                                                            \
    _Pragma("unroll")                                          \
    for (int k = 0; k < ROWS; ++k) {                           \
      s[k] = fmaf(fmaxf(a[k].x + (vv).x, 0.f), w.x, s[k]);     \
      s[k] = fmaf(fmaxf(a[k].y + (vv).y, 0.f), w.y, s[k]);     \
      s[k] = fmaf(fmaxf(a[k].z + (vv).z, 0.f), w.z, s[k]);     \
      s[k] = fmaf(fmaxf(a[k].w + (vv).w, 0.f), w.w, s[k]);     \
    }                                                          \
  }

  float4 v = vp[0];
  #pragma unroll
  for (int j = 0; j < JCL - 1; ++j) {           // branch-free preload pipeline
    float4 vn = vp[(j + 1) * (HID / 4)];
    PAIR_BODY(v);
    v = vn;
  }
  PAIR_BODY(v);
#undef PAIR_BODY

  #pragma unroll
  for (int off = 32; off > 0; off >>= 1) {
    #pragma unroll
    for (int k = 0; k < ROWS; ++k) s[k] += __shfl_down(s[k], off);
  }
  if (lane == 0) {
    float* pp = partial + (b * NJC + jc) * L_DIM;
    #pragma unroll
    for (int k = 0; k < ROWS; ++k) pp[wi + k * LT] = s[k];
  }
}

// Phase 3 (round-4 exact): out[b] = sum over NJC*L partials + L*L*b2
__global__ __launch_bounds__(256) void reduce_kernel(
    const float* __restrict__ partial, const float* __restrict__ b2,
    float* __restrict__ out) {
  const int b = blockIdx.x;
  const int t = threadIdx.x;
  float acc = 0.0f;
  for (int idx = t; idx < NJC * L_DIM; idx += 256)
    acc += partial[b * NJC * L_DIM + idx];
  #pragma unroll
  for (int off = 32; off > 0; off >>= 1) acc += __shfl_down(acc, off);
  __shared__ float sred[4];
  if ((t & 63) == 0) sred[t >> 6] = acc;
  __syncthreads();
  if (t == 0)
    out[b] = sred[0] + sred[1] + sred[2] + sred[3]
           + (float)(L_DIM * L_DIM) * b2[0];
}

extern "C" void kernel_launch(void* const* d_in, const int* in_sizes, int n_in,
                              void* d_out, int out_size, void* d_ws, size_t ws_size,
                              hipStream_t stream) {
  const float* f1 = (const float*)d_in[0];   // [B, C, 14, 14]
  const float* f2 = (const float*)d_in[1];
  const float* W1 = (const float*)d_in[2];   // [2C, HID]
  const float* b1 = (const float*)d_in[3];   // [HID]
  const float* W2 = (const float*)d_in[4];   // [HID, 1]
  const float* b2 = (const float*)d_in[5];   // [1]
  float* out = (float*)d_out;                // [B, 1]

  float* p1      = (float*)d_ws;
  float* p2      = p1 + P_ELEMS;
  float* partial = p2 + P_ELEMS;

  dim3 g1(B_DIM * NLG, 2);                   // (b, 7-l-group) x side = (224, 2)
  compute_p_kernel<<<g1, 256, 0, stream>>>(f1, f2, W1, b1, p1, p2);

  pair_kernel<<<PAIR_BLOCKS, 256, 0, stream>>>(p1, p2, W2, partial);

  reduce_kernel<<<B_DIM, 256, 0, stream>>>(partial, b2, out);
}